// Round 1
// baseline (573.364 us; speedup 1.0000x reference)
//
#include <hip/hip_runtime.h>

#define Bn 64
#define Nn 1024
#define Cc 128

typedef _Float16 h8 __attribute__((ext_vector_type(8)));
typedef float f4v __attribute__((ext_vector_type(4)));
typedef unsigned long long u64;

// ---------------- featurize: x0 = nf @ W_in (fp16 grouped layout), ai/aj + exp tables ----------------
// grouped layout per batch: element (n,c) at ((n>>3)*128 + c)*8 + (n&7)
__global__ __launch_bounds__(256) void k_feat(
    const float* __restrict__ nf, const float* __restrict__ Win,
    const float* __restrict__ asrc, const float* __restrict__ adst,
    _Float16* __restrict__ X0, float* __restrict__ ai, float* __restrict__ aj,
    float* __restrict__ E, float* __restrict__ G, float* __restrict__ F, float* __restrict__ H) {
  int g = blockIdx.x; int b = g >> 7; int n0 = (g & 127) << 3;
  int t = threadIdx.x; int c = t >> 1; int h = t & 1;
  float w0 = Win[c], w1 = Win[Cc + c], w2 = Win[2 * Cc + c];
  float as_ = asrc[c], ad = adst[c];
  float ps[4], pd[4];
  _Float16 hv[4];
  #pragma unroll
  for (int r = 0; r < 4; r++) {
    int n = n0 + (h << 2) + r;
    const float* p = nf + ((size_t)(b << 10) + n) * 3;
    float x = p[0] * w0 + p[1] * w1 + p[2] * w2;
    hv[r] = (_Float16)x; ps[r] = x * as_; pd[r] = x * ad;
  }
  *(uint2*)(X0 + ((size_t)b << 17) + ((size_t)(g & 127) << 10) + (c << 3) + (h << 2)) = *(uint2*)hv;
  #pragma unroll
  for (int off = 32; off > 1; off >>= 1) {
    #pragma unroll
    for (int r = 0; r < 4; r++) { ps[r] += __shfl_down(ps[r], off, 64); pd[r] += __shfl_down(pd[r], off, 64); }
  }
  __shared__ float red[4][2][4][2];
  int lane = t & 63, wv = t >> 6;
  if (lane < 2) {
    #pragma unroll
    for (int r = 0; r < 4; r++) { red[wv][lane][r][0] = ps[r]; red[wv][lane][r][1] = pd[r]; }
  }
  __syncthreads();
  if (t < 8) {
    int hh = t >> 2, r = t & 3;
    float sa = 0.f, sd = 0.f;
    #pragma unroll
    for (int w = 0; w < 4; w++) { sa += red[w][hh][r][0]; sd += red[w][hh][r][1]; }
    int gi = (b << 10) + n0 + t;
    ai[gi] = sa; aj[gi] = sd;
    E[gi] = __expf(sa); G[gi] = __expf(0.2f * sa);
    F[gi] = __expf(sd); H[gi] = __expf(0.2f * sd);
  }
}

// ---------------- layer-2 scores from fp16 grouped x1 ----------------
__global__ __launch_bounds__(256) void k_scores2(
    const _Float16* __restrict__ X1,
    const float* __restrict__ asrc, const float* __restrict__ adst,
    float* __restrict__ ai, float* __restrict__ aj,
    float* __restrict__ E, float* __restrict__ G, float* __restrict__ F, float* __restrict__ H) {
  int g = blockIdx.x; int b = g >> 7; int n0 = (g & 127) << 3;
  int t = threadIdx.x; int c = t >> 1; int h = t & 1;
  float as_ = asrc[c], ad = adst[c];
  uint2 raw = *(const uint2*)(X1 + ((size_t)b << 17) + ((size_t)(g & 127) << 10) + (c << 3) + (h << 2));
  const _Float16* hp = (const _Float16*)&raw;
  float ps[4], pd[4];
  #pragma unroll
  for (int r = 0; r < 4; r++) { float x = (float)hp[r]; ps[r] = x * as_; pd[r] = x * ad; }
  #pragma unroll
  for (int off = 32; off > 1; off >>= 1) {
    #pragma unroll
    for (int r = 0; r < 4; r++) { ps[r] += __shfl_down(ps[r], off, 64); pd[r] += __shfl_down(pd[r], off, 64); }
  }
  __shared__ float red[4][2][4][2];
  int lane = t & 63, wv = t >> 6;
  if (lane < 2) {
    #pragma unroll
    for (int r = 0; r < 4; r++) { red[wv][lane][r][0] = ps[r]; red[wv][lane][r][1] = pd[r]; }
  }
  __syncthreads();
  if (t < 8) {
    int hh = t >> 2, r = t & 3;
    float sa = 0.f, sd = 0.f;
    #pragma unroll
    for (int w = 0; w < 4; w++) { sa += red[w][hh][r][0]; sd += red[w][hh][r][1]; }
    int gi = (b << 10) + n0 + t;
    ai[gi] = sa; aj[gi] = sd;
    E[gi] = __expf(sa); G[gi] = __expf(0.2f * sa);
    F[gi] = __expf(sd); H[gi] = __expf(0.2f * sd);
  }
}

// ------- MFMA aggregation, ZERO-barrier K-loop -------
// out[i,c] = relu( (1/den_i) * sum_j alpha_ij * x[j,c] ),  den_i = sum_j alpha_ij
// Restructure vs previous version:
//  * B operand read DIRECTLY from global: grouped X layout is byte-identical to the
//    old sB copy, so fragment addressing works on global pointers (L2-resident,
//    256 KB/batch). No global->LDS staging, no vmcnt(0) drain, no barrier.
//  * A operand generated IN-REGISTER in fragment layout: lane (m,quad) of wave
//    (wi,wc) computes alpha[wi*32+m][jt+quad*8+e] and alpha[wi*32+16+m][...]
//    (waves sharing wi duplicate this VALU work — the price of zero sync).
//  * Row denominator: in-wave shfl_xor quad-reduce, no LDS round-trip.
// K-loop has NO __syncthreads: 12 waves/CU run fully independently.
template <int LAYER>
__global__ __launch_bounds__(256, 3) void k_agg(
    const _Float16* __restrict__ X, const int* __restrict__ adj,
    const float* __restrict__ ai, const float* __restrict__ E, const float* __restrict__ G,
    const float* __restrict__ aj, const float* __restrict__ F, const float* __restrict__ H,
    u64* __restrict__ pm, _Float16* __restrict__ Y, float* __restrict__ xmp) {
  __shared__ __align__(16) char smem[33792];
  float* s_aj = (float*)smem;                            // 4 KB
  float* s_F  = (float*)(smem + 4096);                   // 4 KB
  float* s_H  = (float*)(smem + 8192);                   // 4 KB
  unsigned char* s_pm = (unsigned char*)(smem + 12288);  // 64 rows x 152 B
  float* tile = (float*)smem;                            // epilogue overlay [64][132] = 33792 B

  const int b = blockIdx.y, i0 = blockIdx.x << 6;
  const int tid = threadIdx.x;
  const int lane = tid & 63, wv = tid >> 6;
  const int m = lane & 15, quad = lane >> 4;
  const int wi = wv >> 1, wc = wv & 1;
  const int gbase = b << 10;

  // stage col-side arrays (aj, F, H) for all 1024 j
  ((float4*)s_aj)[tid] = ((const float4*)(aj + gbase))[tid];
  ((float4*)s_F)[tid]  = ((const float4*)(F + gbase))[tid];
  ((float4*)s_H)[tid]  = ((const float4*)(H + gbase))[tid];

  if (LAYER == 1) {
    // fused adjacency read + bit-pack: wave wv handles rows wv*16..wv*16+15.
    ushort* pmu = (ushort*)pm;
    #pragma unroll 2
    for (int pass = 0; pass < 16; ++pass) {
      int r = (wv << 4) + pass;
      const uint4* arow = (const uint4*)(adj + ((size_t)(gbase + i0 + r) << 10));
      uint4 v0 = arow[(lane << 2) | 0], v1 = arow[(lane << 2) | 1];
      uint4 v2 = arow[(lane << 2) | 2], v3 = arow[(lane << 2) | 3];
      unsigned int bits =
          (v0.x) | (v0.y << 1) | (v0.z << 2) | (v0.w << 3) |
          (v1.x << 4) | (v1.y << 5) | (v1.z << 6) | (v1.w << 7) |
          (v2.x << 8) | (v2.y << 9) | (v2.z << 10) | (v2.w << 11) |
          (v3.x << 12) | (v3.y << 13) | (v3.z << 14) | (v3.w << 15);
      *(ushort*)(s_pm + r * 152 + (lane << 1)) = (ushort)bits;
      pmu[((size_t)(gbase + i0 + r) << 6) + lane] = (ushort)bits;
    }
  } else {
    const u64* pmg = pm + (((size_t)(gbase + i0)) << 4);
    #pragma unroll
    for (int k = tid; k < 1024; k += 256) {
      int r = k >> 4, w = k & 15;
      *(u64*)(s_pm + r * 152 + (w << 3)) = pmg[k];
    }
  }

  // per-lane row constants: this lane owns output rows r0 = wi*32+m and r0+16
  const int r0 = (wi << 5) + m;
  const int gi0 = gbase + i0 + r0;
  const float ai0 = ai[gi0],      E0c = E[gi0],      G0c = G[gi0];
  const float ai1 = ai[gi0 + 16], E1c = E[gi0 + 16], G1c = G[gi0 + 16];
  float dsum0 = 0.f, dsum1 = 0.f;

  f4v acc[2][4];
  #pragma unroll
  for (int a = 0; a < 2; a++)
    #pragma unroll
    for (int ct = 0; ct < 4; ct++) { f4v z = {0.f, 0.f, 0.f, 0.f}; acc[a][ct] = z; }

  // B fragment base: grouped layout => global byte offset == old sB byte offset
  const char* gB = (const char*)(X + ((size_t)b << 17)) + (((quad << 7) + (wc << 6) + m) << 4);
  const unsigned char* pmr0 = s_pm + r0 * 152;
  const unsigned char* pmr1 = pmr0 + 16 * 152;

  __syncthreads();  // staging (s_aj/s_F/s_H/s_pm) visible to all waves

  for (int kt = 0; kt < 32; ++kt) {
    // B fragments straight from global (L2 hit): 4 x 16B per lane
    h8 b0 = *(const h8*)(gB);
    h8 b1 = *(const h8*)(gB + 256);
    h8 b2 = *(const h8*)(gB + 512);
    h8 b3 = *(const h8*)(gB + 768);
    gB += 8192;
    // col-side values for j = kt*32 + quad*8 + e  (16-lane broadcast LDS reads)
    const int j0 = (kt << 5) + (quad << 3);
    float aw[8], fw[8], hw[8];
    *(float4*)&aw[0] = *(const float4*)&s_aj[j0]; *(float4*)&aw[4] = *(const float4*)&s_aj[j0 + 4];
    *(float4*)&fw[0] = *(const float4*)&s_F[j0];  *(float4*)&fw[4] = *(const float4*)&s_F[j0 + 4];
    *(float4*)&hw[0] = *(const float4*)&s_H[j0];  *(float4*)&hw[4] = *(const float4*)&s_H[j0 + 4];
    unsigned int mb0 = pmr0[(kt << 2) + quad];
    unsigned int mb1 = pmr1[(kt << 2) + quad];
    // A fragments generated in-register, exactly in MFMA fragment layout
    h8 a0, a1;
    #pragma unroll
    for (int e = 0; e < 8; e++) {
      float ew = aw[e], fe = fw[e], he = hw[e];
      bool p0 = (ai0 + ew) > 0.f;
      float v0 = (p0 ? E0c : G0c) * (p0 ? fe : he);
      v0 = ((mb0 >> e) & 1u) ? v0 : 0.f;
      dsum0 += v0; a0[e] = (_Float16)v0;
      bool p1 = (ai1 + ew) > 0.f;
      float v1 = (p1 ? E1c : G1c) * (p1 ? fe : he);
      v1 = ((mb1 >> e) & 1u) ? v1 : 0.f;
      dsum1 += v1; a1[e] = (_Float16)v1;
    }
    acc[0][0] = __builtin_amdgcn_mfma_f32_16x16x32_f16(a0, b0, acc[0][0], 0, 0, 0);
    acc[1][0] = __builtin_amdgcn_mfma_f32_16x16x32_f16(a1, b0, acc[1][0], 0, 0, 0);
    acc[0][1] = __builtin_amdgcn_mfma_f32_16x16x32_f16(a0, b1, acc[0][1], 0, 0, 0);
    acc[1][1] = __builtin_amdgcn_mfma_f32_16x16x32_f16(a1, b1, acc[1][1], 0, 0, 0);
    acc[0][2] = __builtin_amdgcn_mfma_f32_16x16x32_f16(a0, b2, acc[0][2], 0, 0, 0);
    acc[1][2] = __builtin_amdgcn_mfma_f32_16x16x32_f16(a1, b2, acc[1][2], 0, 0, 0);
    acc[0][3] = __builtin_amdgcn_mfma_f32_16x16x32_f16(a0, b3, acc[0][3], 0, 0, 0);
    acc[1][3] = __builtin_amdgcn_mfma_f32_16x16x32_f16(a1, b3, acc[1][3], 0, 0, 0);
  }

  // denominator: quad-reduce in-wave (lanes m, m+16, m+32, m+48 hold the 4 j-block partials)
  dsum0 += __shfl_xor(dsum0, 16, 64);
  dsum0 += __shfl_xor(dsum0, 32, 64);
  dsum1 += __shfl_xor(dsum1, 16, 64);
  dsum1 += __shfl_xor(dsum1, 32, 64);
  float rd8[2][4];
  #pragma unroll
  for (int r = 0; r < 4; r++) {
    int src = (quad << 2) + r;  // lane src holds den for row wi*32+src (and +16)
    rd8[0][r] = 1.0f / __shfl(dsum0, src, 64);
    rd8[1][r] = 1.0f / __shfl(dsum1, src, 64);
  }

  __syncthreads();  // all waves done reading s_aj/s_F/s_H/s_pm before tile overlay
  // write relu(acc/den) into fp32 tile [64][132]
  #pragma unroll
  for (int a = 0; a < 2; a++)
    #pragma unroll
    for (int ct = 0; ct < 4; ct++)
      #pragma unroll
      for (int r = 0; r < 4; r++) {
        int lr = (wi << 5) + (a << 4) + (quad << 2) + r;
        int c = (wc << 6) + (ct << 4) + m;
        tile[lr * 132 + c] = fmaxf(acc[a][ct][r] * rd8[a][r], 0.f);
      }
  __syncthreads();
  if (LAYER == 1) {
    // coalesced fp16 grouped-layout store: block region is contiguous [i0*128, +8192)
    _Float16 hv[32];
    #pragma unroll
    for (int s = 0; s < 32; s++) {
      int q = (tid << 5) + s;
      int li = ((q >> 10) << 3) + (q & 7), c = (q >> 3) & 127;
      hv[s] = (_Float16)tile[li * 132 + c];
    }
    uint4* o = (uint4*)(Y + ((size_t)b << 17) + ((size_t)i0 << 7) + (tid << 5));
    o[0] = *(uint4*)&hv[0]; o[1] = *(uint4*)&hv[8];
    o[2] = *(uint4*)&hv[16]; o[3] = *(uint4*)&hv[24];
  } else {
    // node-mean partial: column sums -> per-(block,batch) partial slot (deterministic)
    if (tid < 128) {
      float s = 0.f;
      #pragma unroll
      for (int i = 0; i < 64; i++) s += tile[i * 132 + tid];
      xmp[(((b << 4) + blockIdx.x) << 7) + tid] = s;
    }
  }
}

// ---------------- fused MLP head (sums the 16 mean-partials) ----------------
__global__ __launch_bounds__(256) void k_head(
    const float* __restrict__ xmp, const float* __restrict__ W1, const float* __restrict__ b1,
    const float* __restrict__ W2, const float* __restrict__ b2,
    const float* __restrict__ Wpi, const float* __restrict__ bpi,
    const float* __restrict__ Wv, const float* __restrict__ bv,
    float* __restrict__ out) {
  int b = blockIdx.x, t = threadIdx.x;
  __shared__ float xs[128], h1[256], h2[128], red[4];
  if (t < 128) {
    const float* p = xmp + ((size_t)b << 11);
    float s = 0.f;
    #pragma unroll
    for (int xb = 0; xb < 16; xb++) s += p[(xb << 7) + t];
    xs[t] = s * (1.f / 1024.f);
  }
  __syncthreads();
  float s = 0.f;
  #pragma unroll 8
  for (int k = 0; k < 128; k++) s += xs[k] * W1[k * 256 + t];
  h1[t] = fmaxf(s + b1[t], 0.f);
  __syncthreads();
  if (t < 128) {
    float s2 = 0.f;
    #pragma unroll 8
    for (int k = 0; k < 256; k++) s2 += h1[k] * W2[k * 128 + t];
    h2[t] = fmaxf(s2 + b2[t], 0.f);
  }
  __syncthreads();
  float lg[4];
  #pragma unroll
  for (int q = 0; q < 4; q++) {
    int o = t + (q << 8);
    float s3 = 0.f;
    #pragma unroll 8
    for (int k = 0; k < 128; k++) s3 += h2[k] * Wpi[k * 1024 + o];
    lg[q] = s3 + bpi[o];
  }
  float mx = fmaxf(fmaxf(lg[0], lg[1]), fmaxf(lg[2], lg[3]));
  #pragma unroll
  for (int off = 32; off > 0; off >>= 1) mx = fmaxf(mx, __shfl_down(mx, off, 64));
  if ((t & 63) == 0) red[t >> 6] = mx;
  __syncthreads();
  mx = fmaxf(fmaxf(red[0], red[1]), fmaxf(red[2], red[3]));
  __syncthreads();
  float ex[4]; float sum = 0.f;
  #pragma unroll
  for (int q = 0; q < 4; q++) { ex[q] = __expf(lg[q] - mx); sum += ex[q]; }
  #pragma unroll
  for (int off = 32; off > 0; off >>= 1) sum += __shfl_down(sum, off, 64);
  if ((t & 63) == 0) red[t >> 6] = sum;
  __syncthreads();
  sum = red[0] + red[1] + red[2] + red[3];
  float rs = 1.0f / sum;
  #pragma unroll
  for (int q = 0; q < 4; q++) out[((size_t)b << 10) + t + (q << 8)] = ex[q] * rs;
  __syncthreads();
  float vp = (t < 128) ? h2[t] * Wv[t] : 0.f;
  #pragma unroll
  for (int off = 32; off > 0; off >>= 1) vp += __shfl_down(vp, off, 64);
  if ((t & 63) == 0) red[t >> 6] = vp;
  __syncthreads();
  if (t == 0) out[65536 + b] = red[0] + red[1] + red[2] + red[3] + bv[0];
}

extern "C" void kernel_launch(void* const* d_in, const int* in_sizes, int n_in,
                              void* d_out, int out_size, void* d_ws, size_t ws_size,
                              hipStream_t stream) {
  const float* nf    = (const float*)d_in[0];
  const int*   adj   = (const int*)  d_in[1];
  const float* Win   = (const float*)d_in[2];
  const float* asrc  = (const float*)d_in[3];
  const float* adst  = (const float*)d_in[4];
  const float* asrc2 = (const float*)d_in[5];
  const float* adst2 = (const float*)d_in[6];
  const float* W1    = (const float*)d_in[7];
  const float* b1    = (const float*)d_in[8];
  const float* W2    = (const float*)d_in[9];
  const float* b2    = (const float*)d_in[10];
  const float* Wpi   = (const float*)d_in[11];
  const float* bpi   = (const float*)d_in[12];
  const float* Wv    = (const float*)d_in[13];
  const float* bv    = (const float*)d_in[14];
  float* out = (float*)d_out;

  char* ws = (char*)d_ws;
  _Float16* x0 = (_Float16*)(ws);                                // 16.78 MB
  _Float16* x1 = (_Float16*)(ws + 16777216);                     // 16.78 MB
  u64* pm = (u64*)(ws + 33554432);                               // 8.39 MB
  char* S = ws + 41943040;
  float* ai1 = (float*)(S + 0 * 262144);
  float* aj1 = (float*)(S + 1 * 262144);
  float* E1  = (float*)(S + 2 * 262144);
  float* G1  = (float*)(S + 3 * 262144);
  float* F1  = (float*)(S + 4 * 262144);
  float* H1  = (float*)(S + 5 * 262144);
  float* ai2 = (float*)(S + 6 * 262144);
  float* aj2 = (float*)(S + 7 * 262144);
  float* E2  = (float*)(S + 8 * 262144);
  float* G2  = (float*)(S + 9 * 262144);
  float* F2  = (float*)(S + 10 * 262144);
  float* H2  = (float*)(S + 11 * 262144);
  float* xmp = (float*)(S + 12 * 262144);                        // 512 KB partials

  k_feat<<<8192, 256, 0, stream>>>(nf, Win, asrc, adst, x0, ai1, aj1, E1, G1, F1, H1);
  dim3 ag(16, Bn);
  k_agg<1><<<ag, 256, 0, stream>>>(x0, adj, ai1, E1, G1, aj1, F1, H1, pm, x1, nullptr);
  k_scores2<<<8192, 256, 0, stream>>>(x1, asrc2, adst2, ai2, aj2, E2, G2, F2, H2);
  k_agg<2><<<ag, 256, 0, stream>>>(x1, nullptr, ai2, E2, G2, aj2, F2, H2, pm, nullptr, xmp);
  k_head<<<Bn, 256, 0, stream>>>(xmp, W1, b1, W2, b2, Wpi, bpi, Wv, bv, out);
}

// Round 2
// 564.643 us; speedup vs baseline: 1.0154x; 1.0154x over previous
//
#include <hip/hip_runtime.h>

#define Bn 64
#define Nn 1024
#define Cc 128

typedef _Float16 h8 __attribute__((ext_vector_type(8)));
typedef float f4v __attribute__((ext_vector_type(4)));
typedef unsigned long long u64;

// ---------------- featurize: x0 = nf @ W_in (fp16 grouped layout), ai/aj + exp tables ----------------
// grouped layout per batch: element (n,c) at ((n>>3)*128 + c)*8 + (n&7)
__global__ __launch_bounds__(256) void k_feat(
    const float* __restrict__ nf, const float* __restrict__ Win,
    const float* __restrict__ asrc, const float* __restrict__ adst,
    _Float16* __restrict__ X0, float* __restrict__ ai, float* __restrict__ aj,
    float* __restrict__ E, float* __restrict__ G, float* __restrict__ F, float* __restrict__ H) {
  int g = blockIdx.x; int b = g >> 7; int n0 = (g & 127) << 3;
  int t = threadIdx.x; int c = t >> 1; int h = t & 1;
  __shared__ float sNf[24];
  if (t < 24) sNf[t] = nf[((size_t)(b << 10) + n0) * 3 + t];
  float w0 = Win[c], w1 = Win[Cc + c], w2 = Win[2 * Cc + c];
  float as_ = asrc[c], ad = adst[c];
  __syncthreads();
  float ps[4], pd[4];
  _Float16 hv[4];
  #pragma unroll
  for (int r = 0; r < 4; r++) {
    const float* p = sNf + ((h << 2) + r) * 3;
    float x = p[0] * w0 + p[1] * w1 + p[2] * w2;
    hv[r] = (_Float16)x; ps[r] = x * as_; pd[r] = x * ad;
  }
  *(uint2*)(X0 + ((size_t)b << 17) + ((size_t)(g & 127) << 10) + (c << 3) + (h << 2)) = *(uint2*)hv;
  #pragma unroll
  for (int off = 32; off > 1; off >>= 1) {
    #pragma unroll
    for (int r = 0; r < 4; r++) { ps[r] += __shfl_down(ps[r], off, 64); pd[r] += __shfl_down(pd[r], off, 64); }
  }
  __shared__ float red[4][2][4][2];
  int lane = t & 63, wv = t >> 6;
  if (lane < 2) {
    #pragma unroll
    for (int r = 0; r < 4; r++) { red[wv][lane][r][0] = ps[r]; red[wv][lane][r][1] = pd[r]; }
  }
  __syncthreads();
  if (t < 8) {
    int hh = t >> 2, r = t & 3;
    float sa = 0.f, sd = 0.f;
    #pragma unroll
    for (int w = 0; w < 4; w++) { sa += red[w][hh][r][0]; sd += red[w][hh][r][1]; }
    int gi = (b << 10) + n0 + t;
    ai[gi] = sa; aj[gi] = sd;
    E[gi] = __expf(sa); G[gi] = __expf(0.2f * sa);
    F[gi] = __expf(sd); H[gi] = __expf(0.2f * sd);
  }
}

// ------- MFMA aggregation: zero-barrier K-loop + 1-deep software pipeline -------
// out[i,c] = relu( (1/den_i) * sum_j alpha_ij * x[j,c] ),  den_i = sum_j alpha_ij
//  * B operand straight from global (grouped layout == fragment layout); per-batch
//    slice (256 KB) is L2/L1-resident. XCD swizzle (b = blockIdx.x & 63) pins all
//    16 tiles of a batch to one XCD -> X fetched from HBM once, L2-served after.
//  * A operand (alpha) generated in-register in exact fragment layout.
//  * Explicit 1-deep pipeline: LOADK(kt+1) issued before COMP(kt) so the 4 global
//    loads + 6 LDS reads + 2 mask bytes are in flight under ~300cy of VALU+MFMA.
//    Prefetch at kt=32 is unguarded: reads land in valid ws/LDS memory, unused.
//  * LAYER 1 fuses the layer-2 score computation (k_scores2) into the epilogue:
//    scores from the fp32 tile (closer to reference than the old fp16 path).
template <int LAYER>
__global__ __launch_bounds__(256, 3) void k_agg(
    const _Float16* __restrict__ X, const int* __restrict__ adj,
    const float* __restrict__ ai, const float* __restrict__ E, const float* __restrict__ G,
    const float* __restrict__ aj, const float* __restrict__ F, const float* __restrict__ H,
    u64* __restrict__ pm, _Float16* __restrict__ Y, float* __restrict__ xmp,
    const float* __restrict__ as2, const float* __restrict__ ad2,
    float* __restrict__ ai2o, float* __restrict__ aj2o,
    float* __restrict__ E2o, float* __restrict__ G2o,
    float* __restrict__ F2o, float* __restrict__ H2o) {
  __shared__ __align__(16) char smem[34816];
  float* s_aj = (float*)smem;                            // 4 KB
  float* s_F  = (float*)(smem + 4096);                   // 4 KB
  float* s_H  = (float*)(smem + 8192);                   // 4 KB
  unsigned char* s_pm = (unsigned char*)(smem + 12288);  // 64 rows x 152 B
  float* tile = (float*)smem;                            // epilogue overlay [64][132] = 33792 B
  float* s_as2 = (float*)(smem + 33792);                 // 512 B (LAYER 1 only)
  float* s_ad2 = (float*)(smem + 34304);                 // 512 B

  // XCD-locality swizzle: batch = lin & 63 -> batch b's 16 tiles on XCD (b % 8)
  const int lin = blockIdx.x;
  const int b = lin & 63, tile_id = lin >> 6, i0 = tile_id << 6;
  const int tid = threadIdx.x;
  const int lane = tid & 63, wv = tid >> 6;
  const int m = lane & 15, quad = lane >> 4;
  const int wi = wv >> 1, wc = wv & 1;
  const int gbase = b << 10;

  // stage col-side arrays (aj, F, H) for all 1024 j
  ((float4*)s_aj)[tid] = ((const float4*)(aj + gbase))[tid];
  ((float4*)s_F)[tid]  = ((const float4*)(F + gbase))[tid];
  ((float4*)s_H)[tid]  = ((const float4*)(H + gbase))[tid];
  if (LAYER == 1 && tid < 128) { s_as2[tid] = as2[tid]; s_ad2[tid] = ad2[tid]; }

  if (LAYER == 1) {
    // fused adjacency read + bit-pack: wave wv handles rows wv*16..wv*16+15.
    ushort* pmu = (ushort*)pm;
    #pragma unroll 2
    for (int pass = 0; pass < 16; ++pass) {
      int r = (wv << 4) + pass;
      const uint4* arow = (const uint4*)(adj + ((size_t)(gbase + i0 + r) << 10));
      uint4 v0 = arow[(lane << 2) | 0], v1 = arow[(lane << 2) | 1];
      uint4 v2 = arow[(lane << 2) | 2], v3 = arow[(lane << 2) | 3];
      unsigned int bits =
          (v0.x) | (v0.y << 1) | (v0.z << 2) | (v0.w << 3) |
          (v1.x << 4) | (v1.y << 5) | (v1.z << 6) | (v1.w << 7) |
          (v2.x << 8) | (v2.y << 9) | (v2.z << 10) | (v2.w << 11) |
          (v3.x << 12) | (v3.y << 13) | (v3.z << 14) | (v3.w << 15);
      *(ushort*)(s_pm + r * 152 + (lane << 1)) = (ushort)bits;
      pmu[((size_t)(gbase + i0 + r) << 6) + lane] = (ushort)bits;
    }
  } else {
    const u64* pmg = pm + (((size_t)(gbase + i0)) << 4);
    #pragma unroll
    for (int k = tid; k < 1024; k += 256) {
      int r = k >> 4, w = k & 15;
      *(u64*)(s_pm + r * 152 + (w << 3)) = pmg[k];
    }
  }

  // per-lane row constants: this lane owns output rows r0 = wi*32+m and r0+16
  const int r0 = (wi << 5) + m;
  const int gi0 = gbase + i0 + r0;
  const float ai0 = ai[gi0],      E0c = E[gi0],      G0c = G[gi0];
  const float ai1 = ai[gi0 + 16], E1c = E[gi0 + 16], G1c = G[gi0 + 16];
  float dsum0 = 0.f, dsum1 = 0.f;

  f4v acc[2][4];
  #pragma unroll
  for (int a = 0; a < 2; a++)
    #pragma unroll
    for (int ct = 0; ct < 4; ct++) { f4v z = {0.f, 0.f, 0.f, 0.f}; acc[a][ct] = z; }

  // B fragment base: grouped layout => global byte offset == fragment byte offset
  const char* gB = (const char*)(X + ((size_t)b << 17)) + (((quad << 7) + (wc << 6) + m) << 4);
  const unsigned char* pmr0 = s_pm + r0 * 152;
  const unsigned char* pmr1 = pmr0 + 16 * 152;

  auto LOADK = [&](int kt, h8& B0, h8& B1, h8& B2, h8& B3,
                   float4& W0, float4& W1, float4& Fw0, float4& Fw1,
                   float4& Hw0, float4& Hw1, unsigned& M0, unsigned& M1) {
    const char* gp = gB + ((size_t)kt << 13);
    B0 = *(const h8*)gp;          B1 = *(const h8*)(gp + 256);
    B2 = *(const h8*)(gp + 512);  B3 = *(const h8*)(gp + 768);
    const int j0 = (kt << 5) + (quad << 3);
    W0  = *(const float4*)&s_aj[j0]; W1  = *(const float4*)&s_aj[j0 + 4];
    Fw0 = *(const float4*)&s_F[j0];  Fw1 = *(const float4*)&s_F[j0 + 4];
    Hw0 = *(const float4*)&s_H[j0];  Hw1 = *(const float4*)&s_H[j0 + 4];
    M0 = pmr0[(kt << 2) + quad];     M1 = pmr1[(kt << 2) + quad];
  };
  auto COMP = [&](h8 B0, h8 B1, h8 B2, h8 B3,
                  float4 W0, float4 W1, float4 Fw0, float4 Fw1,
                  float4 Hw0, float4 Hw1, unsigned M0, unsigned M1) {
    float aw[8], fw[8], hw[8];
    *(float4*)&aw[0] = W0;  *(float4*)&aw[4] = W1;
    *(float4*)&fw[0] = Fw0; *(float4*)&fw[4] = Fw1;
    *(float4*)&hw[0] = Hw0; *(float4*)&hw[4] = Hw1;
    h8 a0, a1;
    #pragma unroll
    for (int e = 0; e < 8; e++) {
      float ew = aw[e], fe = fw[e], he = hw[e];
      bool p0 = (ai0 + ew) > 0.f;
      float v0 = (p0 ? E0c : G0c) * (p0 ? fe : he);
      v0 = ((M0 >> e) & 1u) ? v0 : 0.f;
      dsum0 += v0; a0[e] = (_Float16)v0;
      bool p1 = (ai1 + ew) > 0.f;
      float v1 = (p1 ? E1c : G1c) * (p1 ? fe : he);
      v1 = ((M1 >> e) & 1u) ? v1 : 0.f;
      dsum1 += v1; a1[e] = (_Float16)v1;
    }
    acc[0][0] = __builtin_amdgcn_mfma_f32_16x16x32_f16(a0, B0, acc[0][0], 0, 0, 0);
    acc[1][0] = __builtin_amdgcn_mfma_f32_16x16x32_f16(a1, B0, acc[1][0], 0, 0, 0);
    acc[0][1] = __builtin_amdgcn_mfma_f32_16x16x32_f16(a0, B1, acc[0][1], 0, 0, 0);
    acc[1][1] = __builtin_amdgcn_mfma_f32_16x16x32_f16(a1, B1, acc[1][1], 0, 0, 0);
    acc[0][2] = __builtin_amdgcn_mfma_f32_16x16x32_f16(a0, B2, acc[0][2], 0, 0, 0);
    acc[1][2] = __builtin_amdgcn_mfma_f32_16x16x32_f16(a1, B2, acc[1][2], 0, 0, 0);
    acc[0][3] = __builtin_amdgcn_mfma_f32_16x16x32_f16(a0, B3, acc[0][3], 0, 0, 0);
    acc[1][3] = __builtin_amdgcn_mfma_f32_16x16x32_f16(a1, B3, acc[1][3], 0, 0, 0);
  };

  __syncthreads();  // staging (s_aj/s_F/s_H/s_pm/s_as2/s_ad2) visible to all waves

  // ping-pong register sets; prefetch kt+1 before computing kt
  h8 Ab0, Ab1, Ab2, Ab3; float4 Aw0, Aw1, Af0, Af1, Ah0, Ah1; unsigned Am0, Am1;
  h8 Bb0, Bb1, Bb2, Bb3; float4 Bw0, Bw1, Bf0, Bf1, Bh0, Bh1; unsigned Bm0, Bm1;
  LOADK(0, Ab0, Ab1, Ab2, Ab3, Aw0, Aw1, Af0, Af1, Ah0, Ah1, Am0, Am1);
  for (int kt = 0; kt < 32; kt += 2) {
    LOADK(kt + 1, Bb0, Bb1, Bb2, Bb3, Bw0, Bw1, Bf0, Bf1, Bh0, Bh1, Bm0, Bm1);
    COMP(Ab0, Ab1, Ab2, Ab3, Aw0, Aw1, Af0, Af1, Ah0, Ah1, Am0, Am1);
    LOADK(kt + 2, Ab0, Ab1, Ab2, Ab3, Aw0, Aw1, Af0, Af1, Ah0, Ah1, Am0, Am1);  // kt=30 -> 32: benign OOB prefetch
    COMP(Bb0, Bb1, Bb2, Bb3, Bw0, Bw1, Bf0, Bf1, Bh0, Bh1, Bm0, Bm1);
  }

  // denominator: quad-reduce in-wave (lanes m, m+16, m+32, m+48 hold the 4 j-block partials)
  dsum0 += __shfl_xor(dsum0, 16, 64);
  dsum0 += __shfl_xor(dsum0, 32, 64);
  dsum1 += __shfl_xor(dsum1, 16, 64);
  dsum1 += __shfl_xor(dsum1, 32, 64);
  float rd8[2][4];
  #pragma unroll
  for (int r = 0; r < 4; r++) {
    int src = (quad << 2) + r;  // lane src holds den for row wi*32+src (and +16)
    rd8[0][r] = 1.0f / __shfl(dsum0, src, 64);
    rd8[1][r] = 1.0f / __shfl(dsum1, src, 64);
  }

  __syncthreads();  // all waves done reading s_aj/s_F/s_H/s_pm before tile overlay
  // write relu(acc/den) into fp32 tile [64][132]
  #pragma unroll
  for (int a = 0; a < 2; a++)
    #pragma unroll
    for (int ct = 0; ct < 4; ct++)
      #pragma unroll
      for (int r = 0; r < 4; r++) {
        int lr = (wi << 5) + (a << 4) + (quad << 2) + r;
        int c = (wc << 6) + (ct << 4) + m;
        tile[lr * 132 + c] = fmaxf(acc[a][ct][r] * rd8[a][r], 0.f);
      }
  __syncthreads();
  if (LAYER == 1) {
    // coalesced fp16 grouped-layout store: block region is contiguous [i0*128, +8192)
    _Float16 hv[32];
    #pragma unroll
    for (int s = 0; s < 32; s++) {
      int q = (tid << 5) + s;
      int li = ((q >> 10) << 3) + (q & 7), c = (q >> 3) & 127;
      hv[s] = (_Float16)tile[li * 132 + c];
    }
    uint4* o = (uint4*)(Y + ((size_t)b << 17) + ((size_t)i0 << 7) + (tid << 5));
    o[0] = *(uint4*)&hv[0]; o[1] = *(uint4*)&hv[8];
    o[2] = *(uint4*)&hv[16]; o[3] = *(uint4*)&hv[24];
    // fused layer-2 scores (replaces k_scores2): row i of this tile, from fp32 values.
    // thread (i = tid>>2, p = tid&3) sums c = p*32..p*32+31; 4-lane xor-reduce.
    {
      int i = tid >> 2, p = tid & 3, cb = p << 5;
      const float* trow = tile + i * 132 + cb;
      float ssrc = 0.f, sdst = 0.f;
      #pragma unroll
      for (int k = 0; k < 32; k += 4) {
        float4 tv = *(const float4*)(trow + k);
        float4 av = *(const float4*)(s_as2 + cb + k);
        float4 dv = *(const float4*)(s_ad2 + cb + k);
        ssrc += tv.x * av.x + tv.y * av.y + tv.z * av.z + tv.w * av.w;
        sdst += tv.x * dv.x + tv.y * dv.y + tv.z * dv.z + tv.w * dv.w;
      }
      ssrc += __shfl_xor(ssrc, 1, 64); ssrc += __shfl_xor(ssrc, 2, 64);
      sdst += __shfl_xor(sdst, 1, 64); sdst += __shfl_xor(sdst, 2, 64);
      int gi = gbase + i0 + i;
      if (p == 0) { ai2o[gi] = ssrc; E2o[gi] = __expf(ssrc); G2o[gi] = __expf(0.2f * ssrc); }
      else if (p == 1) { aj2o[gi] = sdst; F2o[gi] = __expf(sdst); H2o[gi] = __expf(0.2f * sdst); }
    }
  } else {
    // node-mean partial: column sums -> per-(block,batch) partial slot (deterministic)
    if (tid < 128) {
      float s = 0.f;
      #pragma unroll
      for (int i = 0; i < 64; i++) s += tile[i * 132 + tid];
      xmp[(((b << 4) + tile_id) << 7) + tid] = s;
    }
  }
}

// ---------------- fused MLP head (sums the 16 mean-partials) ----------------
__global__ __launch_bounds__(256) void k_head(
    const float* __restrict__ xmp, const float* __restrict__ W1, const float* __restrict__ b1,
    const float* __restrict__ W2, const float* __restrict__ b2,
    const float* __restrict__ Wpi, const float* __restrict__ bpi,
    const float* __restrict__ Wv, const float* __restrict__ bv,
    float* __restrict__ out) {
  int b = blockIdx.x, t = threadIdx.x;
  __shared__ float xs[128], h1[256], h2[128], red[4];
  if (t < 128) {
    const float* p = xmp + ((size_t)b << 11);
    float s = 0.f;
    #pragma unroll
    for (int xb = 0; xb < 16; xb++) s += p[(xb << 7) + t];
    xs[t] = s * (1.f / 1024.f);
  }
  __syncthreads();
  float s = 0.f;
  #pragma unroll 8
  for (int k = 0; k < 128; k++) s += xs[k] * W1[k * 256 + t];
  h1[t] = fmaxf(s + b1[t], 0.f);
  __syncthreads();
  if (t < 128) {
    float s2 = 0.f;
    #pragma unroll 8
    for (int k = 0; k < 256; k++) s2 += h1[k] * W2[k * 128 + t];
    h2[t] = fmaxf(s2 + b2[t], 0.f);
  }
  __syncthreads();
  float lg[4];
  #pragma unroll
  for (int q = 0; q < 4; q++) {
    int o = t + (q << 8);
    float s3 = 0.f;
    #pragma unroll 8
    for (int k = 0; k < 128; k++) s3 += h2[k] * Wpi[k * 1024 + o];
    lg[q] = s3 + bpi[o];
  }
  float mx = fmaxf(fmaxf(lg[0], lg[1]), fmaxf(lg[2], lg[3]));
  #pragma unroll
  for (int off = 32; off > 0; off >>= 1) mx = fmaxf(mx, __shfl_down(mx, off, 64));
  if ((t & 63) == 0) red[t >> 6] = mx;
  __syncthreads();
  mx = fmaxf(fmaxf(red[0], red[1]), fmaxf(red[2], red[3]));
  __syncthreads();
  float ex[4]; float sum = 0.f;
  #pragma unroll
  for (int q = 0; q < 4; q++) { ex[q] = __expf(lg[q] - mx); sum += ex[q]; }
  #pragma unroll
  for (int off = 32; off > 0; off >>= 1) sum += __shfl_down(sum, off, 64);
  if ((t & 63) == 0) red[t >> 6] = sum;
  __syncthreads();
  sum = red[0] + red[1] + red[2] + red[3];
  float rs = 1.0f / sum;
  #pragma unroll
  for (int q = 0; q < 4; q++) out[((size_t)b << 10) + t + (q << 8)] = ex[q] * rs;
  __syncthreads();
  float vp = (t < 128) ? h2[t] * Wv[t] : 0.f;
  #pragma unroll
  for (int off = 32; off > 0; off >>= 1) vp += __shfl_down(vp, off, 64);
  if ((t & 63) == 0) red[t >> 6] = vp;
  __syncthreads();
  if (t == 0) out[65536 + b] = red[0] + red[1] + red[2] + red[3] + bv[0];
}

extern "C" void kernel_launch(void* const* d_in, const int* in_sizes, int n_in,
                              void* d_out, int out_size, void* d_ws, size_t ws_size,
                              hipStream_t stream) {
  const float* nf    = (const float*)d_in[0];
  const int*   adj   = (const int*)  d_in[1];
  const float* Win   = (const float*)d_in[2];
  const float* asrc  = (const float*)d_in[3];
  const float* adst  = (const float*)d_in[4];
  const float* asrc2 = (const float*)d_in[5];
  const float* adst2 = (const float*)d_in[6];
  const float* W1    = (const float*)d_in[7];
  const float* b1    = (const float*)d_in[8];
  const float* W2    = (const float*)d_in[9];
  const float* b2    = (const float*)d_in[10];
  const float* Wpi   = (const float*)d_in[11];
  const float* bpi   = (const float*)d_in[12];
  const float* Wv    = (const float*)d_in[13];
  const float* bv    = (const float*)d_in[14];
  float* out = (float*)d_out;

  char* ws = (char*)d_ws;
  _Float16* x0 = (_Float16*)(ws);                                // 16.78 MB
  _Float16* x1 = (_Float16*)(ws + 16777216);                     // 16.78 MB
  u64* pm = (u64*)(ws + 33554432);                               // 8.39 MB
  char* S = ws + 41943040;
  float* ai1 = (float*)(S + 0 * 262144);
  float* aj1 = (float*)(S + 1 * 262144);
  float* E1  = (float*)(S + 2 * 262144);
  float* G1  = (float*)(S + 3 * 262144);
  float* F1  = (float*)(S + 4 * 262144);
  float* H1  = (float*)(S + 5 * 262144);
  float* ai2 = (float*)(S + 6 * 262144);
  float* aj2 = (float*)(S + 7 * 262144);
  float* E2  = (float*)(S + 8 * 262144);
  float* G2  = (float*)(S + 9 * 262144);
  float* F2  = (float*)(S + 10 * 262144);
  float* H2  = (float*)(S + 11 * 262144);
  float* xmp = (float*)(S + 12 * 262144);                        // 512 KB partials

  k_feat<<<8192, 256, 0, stream>>>(nf, Win, asrc, adst, x0, ai1, aj1, E1, G1, F1, H1);
  k_agg<1><<<1024, 256, 0, stream>>>(x0, adj, ai1, E1, G1, aj1, F1, H1, pm, x1, nullptr,
                                     asrc2, adst2, ai2, aj2, E2, G2, F2, H2);
  k_agg<2><<<1024, 256, 0, stream>>>(x1, nullptr, ai2, E2, G2, aj2, F2, H2, pm, nullptr, xmp,
                                     nullptr, nullptr, nullptr, nullptr, nullptr, nullptr, nullptr, nullptr);
  k_head<<<Bn, 256, 0, stream>>>(xmp, W1, b1, W2, b2, Wpi, bpi, Wv, bv, out);
}

// Round 4
// 505.335 us; speedup vs baseline: 1.1346x; 1.1174x over previous
//
#include <hip/hip_runtime.h>

#define Bn 64
#define Nn 1024
#define Cc 128

typedef _Float16 h8 __attribute__((ext_vector_type(8)));
typedef __fp16 fp16x2 __attribute__((ext_vector_type(2)));
typedef float f4v __attribute__((ext_vector_type(4)));
typedef unsigned long long u64;

// ---------------- featurize + adjacency pack ----------------
// x0 = nf @ W_in (fp16 grouped layout): element (n,c) at ((n>>3)*128 + c)*8 + (n&7)
// E=exp(ai), G=exp(0.2 ai), F=exp(aj), H=exp(0.2 aj)  (ai/aj themselves not needed downstream:
// alpha = mask * max(E_i*F_j, G_i*H_j) since exp(leakyrelu(e)) = max(exp(e), exp(0.2e)))
// Also packs the adjacency rows for this block's 8 nodes into bitmask pm (row-major 128 B/row).
__global__ __launch_bounds__(256) void k_feat(
    const float* __restrict__ nf, const float* __restrict__ Win,
    const float* __restrict__ asrc, const float* __restrict__ adst,
    const int* __restrict__ adj, _Float16* __restrict__ X0, u64* __restrict__ pm,
    float* __restrict__ E, float* __restrict__ G, float* __restrict__ F, float* __restrict__ H) {
  int g = blockIdx.x; int b = g >> 7; int n0 = (g & 127) << 3;
  int t = threadIdx.x; int c = t >> 1; int h = t & 1;
  int lane = t & 63, wv = t >> 6;
  __shared__ float sNf[24];
  if (t < 24) sNf[t] = nf[((size_t)(b << 10) + n0) * 3 + t];
  float w0 = Win[c], w1 = Win[Cc + c], w2 = Win[2 * Cc + c];
  float as_ = asrc[c], ad = adst[c];
  __syncthreads();
  float ps[4], pd[4];
  _Float16 hv[4];
  #pragma unroll
  for (int r = 0; r < 4; r++) {
    const float* p = sNf + ((h << 2) + r) * 3;
    float x = p[0] * w0 + p[1] * w1 + p[2] * w2;
    hv[r] = (_Float16)x; ps[r] = x * as_; pd[r] = x * ad;
  }
  *(uint2*)(X0 + ((size_t)b << 17) + ((size_t)(g & 127) << 10) + (c << 3) + (h << 2)) = *(uint2*)hv;

  // ---- adjacency bit-pack: wave wv packs rows n0+2*wv, n0+2*wv+1 of batch b ----
  {
    ushort* pmu = (ushort*)pm;
    int row = n0 + (wv << 1);
    const uint4* ar = (const uint4*)(adj + (((size_t)(b << 10) + row) << 10));
    #pragma unroll
    for (int rr = 0; rr < 2; rr++) {
      uint4 v0 = ar[(lane << 2) | 0], v1 = ar[(lane << 2) | 1];
      uint4 v2 = ar[(lane << 2) | 2], v3 = ar[(lane << 2) | 3];
      unsigned int bits =
          (v0.x) | (v0.y << 1) | (v0.z << 2) | (v0.w << 3) |
          (v1.x << 4) | (v1.y << 5) | (v1.z << 6) | (v1.w << 7) |
          (v2.x << 8) | (v2.y << 9) | (v2.z << 10) | (v2.w << 11) |
          (v3.x << 12) | (v3.y << 13) | (v3.z << 14) | (v3.w << 15);
      pmu[(((size_t)(b << 10) + row + rr) << 6) + lane] = (ushort)bits;
      ar += 256;  // next row (1024 ints)
    }
  }

  #pragma unroll
  for (int off = 32; off > 1; off >>= 1) {
    #pragma unroll
    for (int r = 0; r < 4; r++) { ps[r] += __shfl_down(ps[r], off, 64); pd[r] += __shfl_down(pd[r], off, 64); }
  }
  __shared__ float red[4][2][4][2];
  if (lane < 2) {
    #pragma unroll
    for (int r = 0; r < 4; r++) { red[wv][lane][r][0] = ps[r]; red[wv][lane][r][1] = pd[r]; }
  }
  __syncthreads();
  if (t < 8) {
    int hh = t >> 2, r = t & 3;
    float sa = 0.f, sd = 0.f;
    #pragma unroll
    for (int w = 0; w < 4; w++) { sa += red[w][hh][r][0]; sd += red[w][hh][r][1]; }
    int gi = (b << 10) + n0 + t;
    E[gi] = __expf(sa); G[gi] = __expf(0.2f * sa);
    F[gi] = __expf(sd); H[gi] = __expf(0.2f * sd);
  }
}

// ------- MFMA aggregation: zero-barrier K-loop, max-trick alpha, ones-MFMA denominator -------
// out[i,c] = relu( (1/den_i) * sum_j alpha_ij * x[j,c] ),  den_i = sum_j alpha_ij
// alpha_ij = mask_ij * max(E_i*F_j, G_i*H_j)   (exact rewrite of exp(leakyrelu) branch)
// A fragment generated in-register in exact MFMA layout; B fragment straight from
// global (grouped layout == fragment layout, XCD-swizzled for L2 residency).
// den computed by accD = mfma(A, ones, accD): reg r of lane (m,quad) = den[row=quad*4+r],
// exactly this lane's C-fragment rows -> no shuffles, no serial dsum chain.
template <int LAYER>
__global__ __launch_bounds__(256, 4) void k_agg(
    const _Float16* __restrict__ X,
    const float* __restrict__ E, const float* __restrict__ G,
    const float* __restrict__ F, const float* __restrict__ H,
    const u64* __restrict__ pm, _Float16* __restrict__ Y, float* __restrict__ xmp,
    const float* __restrict__ as2, const float* __restrict__ ad2,
    float* __restrict__ E2o, float* __restrict__ G2o,
    float* __restrict__ F2o, float* __restrict__ H2o) {
  __shared__ __align__(16) char smem[34816];
  float* s_F  = (float*)smem;                            // 4 KB
  float* s_H  = (float*)(smem + 4096);                   // 4 KB
  unsigned char* s_pm = (unsigned char*)(smem + 8192);   // 64 rows x 152 B
  float* tile = (float*)smem;                            // epilogue overlay [64][132] = 33792 B
  float* s_as2 = (float*)(smem + 33792);                 // 512 B (LAYER 1 only)
  float* s_ad2 = (float*)(smem + 34304);                 // 512 B

  // XCD-locality swizzle: batch = lin & 63 -> batch b's 16 tiles on XCD (b % 8)
  const int lin = blockIdx.x;
  const int b = lin & 63, tile_id = lin >> 6, i0 = tile_id << 6;
  const int tid = threadIdx.x;
  const int lane = tid & 63, wv = tid >> 6;
  const int m = lane & 15, quad = lane >> 4;
  const int wi = wv >> 1, wc = wv & 1;
  const int gbase = b << 10;

  // stage col-side arrays (F, H) and packed mask
  ((float4*)s_F)[tid] = ((const float4*)(F + gbase))[tid];
  ((float4*)s_H)[tid] = ((const float4*)(H + gbase))[tid];
  {
    const u64* pmg = pm + ((size_t)(gbase + i0) << 4);
    #pragma unroll
    for (int k = tid; k < 1024; k += 256) {
      int r = k >> 4, w = k & 15;
      *(u64*)(s_pm + r * 152 + (w << 3)) = pmg[k];
    }
  }
  if (LAYER == 1 && tid < 128) { s_as2[tid] = as2[tid]; s_ad2[tid] = ad2[tid]; }

  // per-lane row constants: this lane owns output rows r0 = wi*32+m and r0+16
  const int r0 = (wi << 5) + m;
  const int gi0 = gbase + i0 + r0;
  const float E0c = E[gi0],      G0c = G[gi0];
  const float E1c = E[gi0 + 16], G1c = G[gi0 + 16];

  f4v acc[2][4];
  #pragma unroll
  for (int a = 0; a < 2; a++)
    #pragma unroll
    for (int ct = 0; ct < 4; ct++) { f4v z = {0.f, 0.f, 0.f, 0.f}; acc[a][ct] = z; }
  f4v accD0 = {0.f, 0.f, 0.f, 0.f}, accD1 = {0.f, 0.f, 0.f, 0.f};
  const h8 kOne = {(_Float16)1.f, (_Float16)1.f, (_Float16)1.f, (_Float16)1.f,
                   (_Float16)1.f, (_Float16)1.f, (_Float16)1.f, (_Float16)1.f};

  // B fragment base: grouped layout => global byte offset == fragment byte offset
  const char* gB = (const char*)(X + ((size_t)b << 17)) + (((quad << 7) + (wc << 6) + m) << 4);
  const unsigned char* pmr0 = s_pm + r0 * 152;
  const unsigned char* pmr1 = pmr0 + 16 * 152;

  __syncthreads();  // staging visible to all waves

  // bit-mask byte -> 4 u32 AND-masks (fp16x2 lanes): spread bits to bytes, widen to halves
  auto expand = [](unsigned mb, unsigned M[4]) {
    unsigned slo = ((mb & 0xFu) * 0x204081u) & 0x01010101u;
    unsigned shi = (((mb >> 4) & 0xFu) * 0x204081u) & 0x01010101u;
    slo *= 0xFFu; shi *= 0xFFu;  // bytes 0/1 -> 0x00/0xFF
    M[0] = __builtin_amdgcn_perm(slo, slo, 0x01010000u);  // [b0,b0,b1,b1]
    M[1] = __builtin_amdgcn_perm(slo, slo, 0x03030202u);  // [b2,b2,b3,b3]
    M[2] = __builtin_amdgcn_perm(shi, shi, 0x01010000u);
    M[3] = __builtin_amdgcn_perm(shi, shi, 0x03030202u);
  };

  auto LOADB = [&](int kt, h8* Bf, unsigned& mb0, unsigned& mb1) {
    const char* gp = gB + ((size_t)kt << 13);
    Bf[0] = *(const h8*)gp;          Bf[1] = *(const h8*)(gp + 256);
    Bf[2] = *(const h8*)(gp + 512);  Bf[3] = *(const h8*)(gp + 768);
    mb0 = pmr0[(kt << 2) + quad];    mb1 = pmr1[(kt << 2) + quad];
  };
  auto COMP = [&](int kt, const h8* Bf, unsigned mb0, unsigned mb1) {
    const int j0 = (kt << 5) + (quad << 3);
    float f[8], hh[8];
    *(float4*)&f[0]  = *(const float4*)&s_F[j0]; *(float4*)&f[4]  = *(const float4*)&s_F[j0 + 4];
    *(float4*)&hh[0] = *(const float4*)&s_H[j0]; *(float4*)&hh[4] = *(const float4*)&s_H[j0 + 4];
    unsigned M0[4], M1[4];
    expand(mb0, M0); expand(mb1, M1);
    union { h8 v; unsigned u[4]; } A0, A1;
    #pragma unroll
    for (int q = 0; q < 4; q++) {
      float u0 = fmaxf(E0c * f[2 * q], G0c * hh[2 * q]);
      float u1 = fmaxf(E0c * f[2 * q + 1], G0c * hh[2 * q + 1]);
      fp16x2 p0 = __builtin_amdgcn_cvt_pkrtz(u0, u1);
      unsigned p0u; __builtin_memcpy(&p0u, &p0, 4);
      A0.u[q] = p0u & M0[q];
      float y0 = fmaxf(E1c * f[2 * q], G1c * hh[2 * q]);
      float y1 = fmaxf(E1c * f[2 * q + 1], G1c * hh[2 * q + 1]);
      fp16x2 p1 = __builtin_amdgcn_cvt_pkrtz(y0, y1);
      unsigned p1u; __builtin_memcpy(&p1u, &p1, 4);
      A1.u[q] = p1u & M1[q];
    }
    acc[0][0] = __builtin_amdgcn_mfma_f32_16x16x32_f16(A0.v, Bf[0], acc[0][0], 0, 0, 0);
    acc[1][0] = __builtin_amdgcn_mfma_f32_16x16x32_f16(A1.v, Bf[0], acc[1][0], 0, 0, 0);
    acc[0][1] = __builtin_amdgcn_mfma_f32_16x16x32_f16(A0.v, Bf[1], acc[0][1], 0, 0, 0);
    acc[1][1] = __builtin_amdgcn_mfma_f32_16x16x32_f16(A1.v, Bf[1], acc[1][1], 0, 0, 0);
    acc[0][2] = __builtin_amdgcn_mfma_f32_16x16x32_f16(A0.v, Bf[2], acc[0][2], 0, 0, 0);
    acc[1][2] = __builtin_amdgcn_mfma_f32_16x16x32_f16(A1.v, Bf[2], acc[1][2], 0, 0, 0);
    acc[0][3] = __builtin_amdgcn_mfma_f32_16x16x32_f16(A0.v, Bf[3], acc[0][3], 0, 0, 0);
    acc[1][3] = __builtin_amdgcn_mfma_f32_16x16x32_f16(A1.v, Bf[3], acc[1][3], 0, 0, 0);
    accD0 = __builtin_amdgcn_mfma_f32_16x16x32_f16(A0.v, kOne, accD0, 0, 0, 0);
    accD1 = __builtin_amdgcn_mfma_f32_16x16x32_f16(A1.v, kOne, accD1, 0, 0, 0);
  };

  // 1-deep software pipeline on the global B fragments + mask bytes
  h8 Bf0[4], Bf1[4]; unsigned m00, m01, m10, m11;
  LOADB(0, Bf0, m00, m01);
  for (int kt = 0; kt < 32; kt += 2) {
    LOADB(kt + 1, Bf1, m10, m11);
    COMP(kt, Bf0, m00, m01);
    LOADB(kt + 2, Bf0, m00, m01);  // kt=30 -> 32: benign prefetch (valid ws memory / in-row pm bytes)
    COMP(kt + 1, Bf1, m10, m11);
  }

  // per-lane reciprocal denominators: reg r of accD{a} = den[row (wi*32 + a*16 + quad*4 + r)]
  float rd8[2][4];
  #pragma unroll
  for (int r = 0; r < 4; r++) { rd8[0][r] = 1.0f / accD0[r]; rd8[1][r] = 1.0f / accD1[r]; }

  __syncthreads();  // all waves done reading s_F/s_H/s_pm before tile overlay
  // write relu(acc/den) into fp32 tile [64][132]
  #pragma unroll
  for (int a = 0; a < 2; a++)
    #pragma unroll
    for (int ct = 0; ct < 4; ct++)
      #pragma unroll
      for (int r = 0; r < 4; r++) {
        int lr = (wi << 5) + (a << 4) + (quad << 2) + r;
        int c = (wc << 6) + (ct << 4) + m;
        tile[lr * 132 + c] = fmaxf(acc[a][ct][r] * rd8[a][r], 0.f);
      }
  __syncthreads();
  if (LAYER == 1) {
    // coalesced fp16 grouped-layout store: block region is contiguous [i0*128, +8192)
    _Float16 hv[32];
    #pragma unroll
    for (int s = 0; s < 32; s++) {
      int q = (tid << 5) + s;
      int li = ((q >> 10) << 3) + (q & 7), c = (q >> 3) & 127;
      hv[s] = (_Float16)tile[li * 132 + c];
    }
    uint4* o = (uint4*)(Y + ((size_t)b << 17) + ((size_t)i0 << 7) + (tid << 5));
    o[0] = *(uint4*)&hv[0]; o[1] = *(uint4*)&hv[8];
    o[2] = *(uint4*)&hv[16]; o[3] = *(uint4*)&hv[24];
    // fused layer-2 scores: row i of this tile, from fp32 values.
    {
      int i = tid >> 2, p = tid & 3, cb = p << 5;
      const float* trow = tile + i * 132 + cb;
      float ssrc = 0.f, sdst = 0.f;
      #pragma unroll
      for (int k = 0; k < 32; k += 4) {
        float4 tv = *(const float4*)(trow + k);
        float4 av = *(const float4*)(s_as2 + cb + k);
        float4 dv = *(const float4*)(s_ad2 + cb + k);
        ssrc += tv.x * av.x + tv.y * av.y + tv.z * av.z + tv.w * av.w;
        sdst += tv.x * dv.x + tv.y * dv.y + tv.z * dv.z + tv.w * dv.w;
      }
      ssrc += __shfl_xor(ssrc, 1, 64); ssrc += __shfl_xor(ssrc, 2, 64);
      sdst += __shfl_xor(sdst, 1, 64); sdst += __shfl_xor(sdst, 2, 64);
      int gi = gbase + i0 + i;
      if (p == 0) { E2o[gi] = __expf(ssrc); G2o[gi] = __expf(0.2f * ssrc); }
      else if (p == 1) { F2o[gi] = __expf(sdst); H2o[gi] = __expf(0.2f * sdst); }
    }
  } else {
    // node-mean partial: column sums -> per-(block,batch) partial slot (deterministic)
    if (tid < 128) {
      float s = 0.f;
      #pragma unroll
      for (int i = 0; i < 64; i++) s += tile[i * 132 + tid];
      xmp[(((b << 4) + tile_id) << 7) + tid] = s;
    }
  }
}

// ---------------- fused MLP head (sums the 16 mean-partials) ----------------
__global__ __launch_bounds__(256) void k_head(
    const float* __restrict__ xmp, const float* __restrict__ W1, const float* __restrict__ b1,
    const float* __restrict__ W2, const float* __restrict__ b2,
    const float* __restrict__ Wpi, const float* __restrict__ bpi,
    const float* __restrict__ Wv, const float* __restrict__ bv,
    float* __restrict__ out) {
  int b = blockIdx.x, t = threadIdx.x;
  __shared__ float xs[128], h1[256], h2[128], red[4];
  if (t < 128) {
    const float* p = xmp + ((size_t)b << 11);
    float s = 0.f;
    #pragma unroll
    for (int xb = 0; xb < 16; xb++) s += p[(xb << 7) + t];
    xs[t] = s * (1.f / 1024.f);
  }
  __syncthreads();
  float s = 0.f;
  #pragma unroll 8
  for (int k = 0; k < 128; k++) s += xs[k] * W1[k * 256 + t];
  h1[t] = fmaxf(s + b1[t], 0.f);
  __syncthreads();
  if (t < 128) {
    float s2 = 0.f;
    #pragma unroll 8
    for (int k = 0; k < 256; k++) s2 += h1[k] * W2[k * 128 + t];
    h2[t] = fmaxf(s2 + b2[t], 0.f);
  }
  __syncthreads();
  float lg[4];
  #pragma unroll
  for (int q = 0; q < 4; q++) {
    int o = t + (q << 8);
    float s3 = 0.f;
    #pragma unroll 8
    for (int k = 0; k < 128; k++) s3 += h2[k] * Wpi[k * 1024 + o];
    lg[q] = s3 + bpi[o];
  }
  float mx = fmaxf(fmaxf(lg[0], lg[1]), fmaxf(lg[2], lg[3]));
  #pragma unroll
  for (int off = 32; off > 0; off >>= 1) mx = fmaxf(mx, __shfl_down(mx, off, 64));
  if ((t & 63) == 0) red[t >> 6] = mx;
  __syncthreads();
  mx = fmaxf(fmaxf(red[0], red[1]), fmaxf(red[2], red[3]));
  __syncthreads();
  float ex[4]; float sum = 0.f;
  #pragma unroll
  for (int q = 0; q < 4; q++) { ex[q] = __expf(lg[q] - mx); sum += ex[q]; }
  #pragma unroll
  for (int off = 32; off > 0; off >>= 1) sum += __shfl_down(sum, off, 64);
  if ((t & 63) == 0) red[t >> 6] = sum;
  __syncthreads();
  sum = red[0] + red[1] + red[2] + red[3];
  float rs = 1.0f / sum;
  #pragma unroll
  for (int q = 0; q < 4; q++) out[((size_t)b << 10) + t + (q << 8)] = ex[q] * rs;
  __syncthreads();
  float vp = (t < 128) ? h2[t] * Wv[t] : 0.f;
  #pragma unroll
  for (int off = 32; off > 0; off >>= 1) vp += __shfl_down(vp, off, 64);
  if ((t & 63) == 0) red[t >> 6] = vp;
  __syncthreads();
  if (t == 0) out[65536 + b] = red[0] + red[1] + red[2] + red[3] + bv[0];
}

extern "C" void kernel_launch(void* const* d_in, const int* in_sizes, int n_in,
                              void* d_out, int out_size, void* d_ws, size_t ws_size,
                              hipStream_t stream) {
  const float* nf    = (const float*)d_in[0];
  const int*   adj   = (const int*)  d_in[1];
  const float* Win   = (const float*)d_in[2];
  const float* asrc  = (const float*)d_in[3];
  const float* adst  = (const float*)d_in[4];
  const float* asrc2 = (const float*)d_in[5];
  const float* adst2 = (const float*)d_in[6];
  const float* W1    = (const float*)d_in[7];
  const float* b1    = (const float*)d_in[8];
  const float* W2    = (const float*)d_in[9];
  const float* b2    = (const float*)d_in[10];
  const float* Wpi   = (const float*)d_in[11];
  const float* bpi   = (const float*)d_in[12];
  const float* Wv    = (const float*)d_in[13];
  const float* bv    = (const float*)d_in[14];
  float* out = (float*)d_out;

  char* ws = (char*)d_ws;
  _Float16* x0 = (_Float16*)(ws);                                // 16.78 MB
  _Float16* x1 = (_Float16*)(ws + 16777216);                     // 16.78 MB
  u64* pm = (u64*)(ws + 33554432);                               // 8.39 MB
  char* S = ws + 41943040;
  float* E1  = (float*)(S + 2 * 262144);
  float* G1  = (float*)(S + 3 * 262144);
  float* F1  = (float*)(S + 4 * 262144);
  float* H1  = (float*)(S + 5 * 262144);
  float* E2  = (float*)(S + 8 * 262144);
  float* G2  = (float*)(S + 9 * 262144);
  float* F2  = (float*)(S + 10 * 262144);
  float* H2  = (float*)(S + 11 * 262144);
  float* xmp = (float*)(S + 12 * 262144);                        // 512 KB partials

  k_feat<<<8192, 256, 0, stream>>>(nf, Win, asrc, adst, adj, x0, pm, E1, G1, F1, H1);
  k_agg<1><<<1024, 256, 0, stream>>>(x0, E1, G1, F1, H1, pm, x1, nullptr,
                                     asrc2, adst2, E2, G2, F2, H2);
  k_agg<2><<<1024, 256, 0, stream>>>(x1, E2, G2, F2, H2, pm, nullptr, xmp,
                                     nullptr, nullptr, nullptr, nullptr, nullptr, nullptr);
  k_head<<<Bn, 256, 0, stream>>>(xmp, W1, b1, W2, b2, Wpi, bpi, Wv, bv, out);
}